// Round 2
// baseline (358.636 us; speedup 1.0000x reference)
//
#include <hip/hip_runtime.h>
#include <math.h>

#define SEQL 8192
#define NH 16
#define HD 1024           // NH * 64
#define TSEL 25

// ---- workspace layout (float offsets) ----
#define OFF_KVPART 0                         // 4*16*4096 = 262144 (zeroed)
#define OFF_KSUM   262144                    // 1024 (zeroed)
#define OFF_ZEND   263168
#define OFF_PK     263168                    // 16*256*64 = 262144
#define OFF_KWT    525312                    // 16*4096 shorts = 32768 floats
#define OFF_KSWZ   558080                    // 16*256*2048 shorts
#define OFF_LUT    131072                    // overlays kvpart (written post-kw_mul consumption? no:
                                             // lut written by score_topk AFTER kw_mul consumed kvpart)

typedef __attribute__((ext_vector_type(8))) short bf16x8;
typedef __attribute__((ext_vector_type(4))) float f32x4;

static __device__ inline short f2bf(float f) {
    union { float f; unsigned u; } c; c.f = f;
    unsigned r = (c.u + 0x7FFFu + ((c.u >> 16) & 1u)) >> 16;
    return (short)r;
}
static __device__ inline bf16x8 cvt8(float4 a, float4 b) {
    bf16x8 r;
    r[0] = f2bf(a.x); r[1] = f2bf(a.y); r[2] = f2bf(a.z); r[3] = f2bf(a.w);
    r[4] = f2bf(b.x); r[5] = f2bf(b.y); r[6] = f2bf(b.z); r[7] = f2bf(b.w);
    return r;
}
static __device__ inline unsigned cvtpk(float a, float b) {
    unsigned r;
    asm("v_cvt_pk_bf16_f32 %0, %1, %2" : "=v"(r) : "v"(a), "v"(b));
    return r;
}
static __device__ inline float exp2a(float x) {
#if __has_builtin(__builtin_amdgcn_exp2f)
    return __builtin_amdgcn_exp2f(x);
#else
    float r; asm("v_exp_f32 %0, %1" : "=v"(r) : "v"(x)); return r;
#endif
}
static __device__ inline void load_lds16(const void* g, void* l) {
    __builtin_amdgcn_global_load_lds((const __attribute__((address_space(1))) unsigned int*)g,
                                     (__attribute__((address_space(3))) unsigned int*)l,
                                     16, 0, 0);
}

// K1: pre-pass — per (h,n): K tile -> bf16 swizzled; V tile -> V^T bf16 swizzled;
// fused pooled_k. UNCHANGED (keeps pk summation order bit-identical -> topk stable).
__global__ __launch_bounds__(256) void prep_kv(const float* __restrict__ k,
                                               const float* __restrict__ v,
                                               short* __restrict__ kswz,
                                               short* __restrict__ vswz,
                                               float* __restrict__ pk) {
    __shared__ float pcol[4][64];
    int b = blockIdx.x;            // h*256 + n
    int h = b >> 8, n = b & 255;
    int t = threadIdx.x;
    {   // K: thread = (r = t>>3, ch = t&7)
        int r = t >> 3, ch = t & 7;
        const float* src = k + (size_t)(n * 32 + r) * HD + h * 64 + ch * 8;
        float4 f0 = *(const float4*)src, f1 = *(const float4*)(src + 4);
        int f = r * 8 + (ch ^ (r & 7));
        *(bf16x8*)(kswz + (size_t)b * 2048 + f * 8) = cvt8(f0, f1);
        float s[8] = { f0.x, f0.y, f0.z, f0.w, f1.x, f1.y, f1.z, f1.w };
        #pragma unroll
        for (int j = 0; j < 8; j++) {
            s[j] += __shfl_xor(s[j], 8, 64);
            s[j] += __shfl_xor(s[j], 16, 64);
            s[j] += __shfl_xor(s[j], 32, 64);
        }
        if ((t & 63) < 8) {
            #pragma unroll
            for (int j = 0; j < 8; j++) pcol[t >> 6][(t & 7) * 8 + j] = s[j];
        }
    }
    {   // V^T
        int c = t >> 6, d = t & 63;
        const float* src = v + (size_t)(n * 32 + c * 8) * HD + h * 64 + d;
        bf16x8 val;
        #pragma unroll
        for (int j = 0; j < 8; j++) val[j] = f2bf(src[(size_t)j * HD]);
        int f = d * 4 + (c ^ ((d >> 1) & 3));
        *(bf16x8*)(vswz + (size_t)b * 2048 + f * 8) = val;
    }
    __syncthreads();
    if (t < 64)
        pk[(size_t)b * 64 + t] =
            (pcol[0][t] + pcol[1][t] + pcol[2][t] + pcol[3][t]) * (1.f / 32.f);
}

// K3: pooled_q fused in (threads t<64 run pool_q's EXACT serial loop -> bit-identical),
// then scores (f64 accum, same order) + top-25 rank select, ballot compaction.
__global__ __launch_bounds__(256) void score_topk(const float* __restrict__ q,
                                                  const float* __restrict__ pk,
                                                  int* __restrict__ lut) {
    __shared__ __align__(16) float pq_s[64];
    __shared__ __align__(16) float s_s[256];
    __shared__ int wcnt[4];
    int b = blockIdx.x;            // h*128 + m
    int h = b >> 7, m = b & 127;
    int t = threadIdx.x;
    int lane = t & 63, w = t >> 6;
    if (t < 64) {
        const float* base = q + (size_t)m * 64 * HD + h * 64 + t;
        float s = 0.f;
        #pragma unroll 8
        for (int r = 0; r < 64; r++) s += base[(size_t)r * HD];
        pq_s[t] = s * (1.f / 64.f);
    }
    __syncthreads();
    const float* kr = pk + ((size_t)h * 256 + t) * 64;
    double acc = 0.0;
    #pragma unroll 8
    for (int d = 0; d < 64; d++) acc += (double)pq_s[d] * (double)kr[d];
    float sc = (float)acc;
    s_s[t] = sc;
    __syncthreads();
    int cnt = 0;
    float si = sc;
    #pragma unroll 4
    for (int j4 = 0; j4 < 64; j4++) {
        float4 sv = *(const float4*)&s_s[j4 * 4];
        int j = j4 * 4;
        cnt += (sv.x > si) || (sv.x == si && (j + 0) < t);
        cnt += (sv.y > si) || (sv.y == si && (j + 1) < t);
        cnt += (sv.z > si) || (sv.z == si && (j + 2) < t);
        cnt += (sv.w > si) || (sv.w == si && (j + 3) < t);
    }
    bool sel = cnt < TSEL;
    unsigned long long bal = __ballot(sel);
    if (lane == 0) wcnt[w] = __popcll(bal);
    __syncthreads();
    if (sel) {
        int off = __popcll(bal & ((1ull << lane) - 1ull));
        for (int i = 0; i < w; i++) off += wcnt[i];
        lut[(size_t)b * TSEL + off] = t;
    }
}

// K4: kvpart += k_fm^T v. Round-0 single-phase structure (2048 blocks, 64 rows,
// ONE barrier, 8 blocks/CU latency hiding) + round-1 register-tile inner loop
// (4d x 4e per thread, 2 per-lane ds_read_b128 per row = 2.5x fewer DS ops than
// round-0's broadcast+scalar mix). Softmax identical to round 0.
__global__ __launch_bounds__(256) void lin_kv(const float* __restrict__ k,
                                              const float* __restrict__ v,
                                              float* __restrict__ kvpart,
                                              float* __restrict__ ksum) {
    __shared__ __align__(16) float kf[64][68];
    __shared__ __align__(16) float vv[64][68];
    int b = blockIdx.x;            // h*128 + chunk
    int h = b >> 7, chunk = b & 127;
    int l0 = chunk * 64;
    int t = threadIdx.x;
    int lane = t & 63, w = t >> 6;
    int row = t >> 2, c16 = (t & 3) * 16;
    const float4* ks4 = (const float4*)(k + (size_t)(l0 + row) * HD + h * 64 + c16);
    const float4* vs4 = (const float4*)(v + (size_t)(l0 + row) * HD + h * 64 + c16);
    {
        float4* vd = (float4*)&vv[row][c16];
        #pragma unroll
        for (int i = 0; i < 4; i++) vd[i] = vs4[i];
    }
    float4 X0 = ks4[0], X1 = ks4[1], X2 = ks4[2], X3 = ks4[3];
    float mx = fmaxf(fmaxf(fmaxf(X0.x, X0.y), fmaxf(X0.z, X0.w)),
                     fmaxf(fmaxf(X1.x, X1.y), fmaxf(X1.z, X1.w)));
    mx = fmaxf(mx, fmaxf(fmaxf(fmaxf(X2.x, X2.y), fmaxf(X2.z, X2.w)),
                         fmaxf(fmaxf(X3.x, X3.y), fmaxf(X3.z, X3.w))));
    mx = fmaxf(mx, __shfl_xor(mx, 1, 64));
    mx = fmaxf(mx, __shfl_xor(mx, 2, 64));
    X0.x = __expf(X0.x - mx); X0.y = __expf(X0.y - mx); X0.z = __expf(X0.z - mx); X0.w = __expf(X0.w - mx);
    X1.x = __expf(X1.x - mx); X1.y = __expf(X1.y - mx); X1.z = __expf(X1.z - mx); X1.w = __expf(X1.w - mx);
    X2.x = __expf(X2.x - mx); X2.y = __expf(X2.y - mx); X2.z = __expf(X2.z - mx); X2.w = __expf(X2.w - mx);
    X3.x = __expf(X3.x - mx); X3.y = __expf(X3.y - mx); X3.z = __expf(X3.z - mx); X3.w = __expf(X3.w - mx);
    float sm = (X0.x + X0.y + X0.z + X0.w) + (X1.x + X1.y + X1.z + X1.w)
             + (X2.x + X2.y + X2.z + X2.w) + (X3.x + X3.y + X3.z + X3.w);
    sm += __shfl_xor(sm, 1, 64);
    sm += __shfl_xor(sm, 2, 64);
    float inv = 1.f / sm;
    X0.x *= inv; X0.y *= inv; X0.z *= inv; X0.w *= inv;
    X1.x *= inv; X1.y *= inv; X1.z *= inv; X1.w *= inv;
    X2.x *= inv; X2.y *= inv; X2.z *= inv; X2.w *= inv;
    X3.x *= inv; X3.y *= inv; X3.z *= inv; X3.w *= inv;
    {
        float4* kd = (float4*)&kf[row][c16];
        kd[0] = X0; kd[1] = X1; kd[2] = X2; kd[3] = X3;
    }
    __syncthreads();
    // 4x4 register tile: d-block = lane&15, e-block = (lane>>4) + w*4
    int d0 = (lane & 15) * 4;
    int e0 = ((lane >> 4) + w * 4) * 4;
    float acc[16];
    #pragma unroll
    for (int i = 0; i < 16; i++) acc[i] = 0.f;
    #pragma unroll 8
    for (int l = 0; l < 64; l++) {
        float4 kd = *(const float4*)&kf[l][d0];
        float4 ve = *(const float4*)&vv[l][e0];
        acc[0]  += kd.x * ve.x; acc[1]  += kd.x * ve.y; acc[2]  += kd.x * ve.z; acc[3]  += kd.x * ve.w;
        acc[4]  += kd.y * ve.x; acc[5]  += kd.y * ve.y; acc[6]  += kd.y * ve.z; acc[7]  += kd.y * ve.w;
        acc[8]  += kd.z * ve.x; acc[9]  += kd.z * ve.y; acc[10] += kd.z * ve.z; acc[11] += kd.z * ve.w;
        acc[12] += kd.w * ve.x; acc[13] += kd.w * ve.y; acc[14] += kd.w * ve.z; acc[15] += kd.w * ve.w;
    }
    float* dst = kvpart + ((size_t)(chunk & 3) * 16 + h) * 4096;
    #pragma unroll
    for (int i = 0; i < 4; i++)
        #pragma unroll
        for (int j = 0; j < 4; j++)
            atomicAdd(&dst[(d0 + i) * 64 + e0 + j], acc[i * 4 + j]);
    if (t < 64) {
        float s = 0.f;
        #pragma unroll 8
        for (int l = 0; l < 64; l++) s += kf[l][t];
        atomicAdd(&ksum[h * 64 + t], s);
    }
}

// K5: reduce partials + KWt = kvsum · W^T (bf16, transposed layout).
// 64 blocks (h x d-quarter); float4 dots; conflict-aware operand mapping.
__global__ __launch_bounds__(256) void kw_mul(const float* __restrict__ kvpart,
                                              const float* __restrict__ W,
                                              short* __restrict__ kwt) {
    __shared__ __align__(16) float kv[16][68];
    __shared__ __align__(16) float wsm[64][68];
    int h = blockIdx.x >> 2, dq = blockIdx.x & 3;
    int t = threadIdx.x;
    for (int i = t; i < 1024; i += 256) {
        int dl = i >> 6, e = i & 63;
        float s = 0.f;
        #pragma unroll
        for (int p = 0; p < 4; p++)
            s += kvpart[((size_t)p * 16 + h) * 4096 + (dq * 16 + dl) * 64 + e];
        kv[dl][e] = s;
    }
    for (int i = t; i < 4096; i += 256) wsm[i >> 6][i & 63] = W[i];
    __syncthreads();
    int lane = t & 63, wi = t >> 6;
    int dl = lane & 15;
    int db = wi * 16 + (lane >> 4) * 4;
    #pragma unroll
    for (int j = 0; j < 4; j++) {
        int dd = db + j;
        float a = 0.f;
        #pragma unroll
        for (int e4 = 0; e4 < 16; e4++) {
            float4 kq = *(const float4*)&kv[dl][e4 * 4];
            float4 wq = *(const float4*)&wsm[dd][e4 * 4];
            a += kq.x * wq.x + kq.y * wq.y + kq.z * wq.z + kq.w * wq.w;
        }
        kwt[(size_t)h * 4096 + dd * 64 + dq * 16 + dl] = f2bf(a);
    }
}

// K6: fused block-sparse attention + linear branch (unchanged from round 1:
// cvt_pk P-pack, ds_write_b64, exp2-folded constant, setprio around MFMA).
__global__ __launch_bounds__(256) void sparse_attn_mfma(const float* __restrict__ q,
                                                        const short* __restrict__ kswz,
                                                        const short* __restrict__ vswz,
                                                        const int* __restrict__ lut,
                                                        const short* __restrict__ kwt,
                                                        const float* __restrict__ ksum,
                                                        const float* __restrict__ bproj,
                                                        float* __restrict__ out) {
    __shared__ __align__(16) short Kb[2][2048];
    __shared__ __align__(16) short Vb[2][2048];
    __shared__ __align__(16) short Pl[64][40];
    __shared__ int lut_s[TSEL];

    int b = blockIdx.x;
    int x = b & 7, jj = b >> 3;
    int h = x * 2 + (jj >> 7);       // XCD-affine
    int m = jj & 127;
    int t = threadIdx.x;
    int lane = t & 63, w = t >> 6;
    int l15 = lane & 15, quad = lane >> 4;

    if (t < TSEL) lut_s[t] = lut[(size_t)(h * 128 + m) * TSEL + t];
    __syncthreads();

    {
        size_t base = (size_t)(h * 256 + lut_s[0]) * 2048;
        load_lds16(kswz + base + t * 8, &Kb[0][t * 8]);
        load_lds16(vswz + base + t * 8, &Vb[0][t * 8]);
        load_lds16(kwt + (size_t)h * 4096 + t * 8, &Kb[1][t * 8]);
        load_lds16(kwt + (size_t)h * 4096 + 2048 + t * 8, &Vb[1][t * 8]);
    }

    const float* qrow = q + (size_t)(m * 64 + w * 16 + l15) * HD + h * 64;
    float4 x0 = *(const float4*)(qrow + quad * 8);
    float4 x1 = *(const float4*)(qrow + quad * 8 + 4);
    float4 x2 = *(const float4*)(qrow + 32 + quad * 8);
    float4 x3 = *(const float4*)(qrow + 32 + quad * 8 + 4);
    bf16x8 qa[2];
    qa[0] = cvt8(x0, x1);
    qa[1] = cvt8(x2, x3);

    float mx = fmaxf(fmaxf(fmaxf(x0.x, x0.y), fmaxf(x0.z, x0.w)),
                     fmaxf(fmaxf(x1.x, x1.y), fmaxf(x1.z, x1.w)));
    mx = fmaxf(mx, fmaxf(fmaxf(fmaxf(x2.x, x2.y), fmaxf(x2.z, x2.w)),
                         fmaxf(fmaxf(x3.x, x3.y), fmaxf(x3.z, x3.w))));
    mx = fmaxf(mx, __shfl_xor(mx, 16, 64));
    mx = fmaxf(mx, __shfl_xor(mx, 32, 64));
    x0.x = __expf(x0.x - mx); x0.y = __expf(x0.y - mx); x0.z = __expf(x0.z - mx); x0.w = __expf(x0.w - mx);
    x1.x = __expf(x1.x - mx); x1.y = __expf(x1.y - mx); x1.z = __expf(x1.z - mx); x1.w = __expf(x1.w - mx);
    x2.x = __expf(x2.x - mx); x2.y = __expf(x2.y - mx); x2.z = __expf(x2.z - mx); x2.w = __expf(x2.w - mx);
    x3.x = __expf(x3.x - mx); x3.y = __expf(x3.y - mx); x3.z = __expf(x3.z - mx); x3.w = __expf(x3.w - mx);
    float sm = (x0.x + x0.y + x0.z + x0.w) + (x1.x + x1.y + x1.z + x1.w)
             + (x2.x + x2.y + x2.z + x2.w) + (x3.x + x3.y + x3.z + x3.w);
    sm += __shfl_xor(sm, 16, 64);
    sm += __shfl_xor(sm, 32, 64);
    float qsc = 1.f / sm;
    float4 ka0 = *(const float4*)(ksum + h * 64 + quad * 8);
    float4 ka1 = *(const float4*)(ksum + h * 64 + quad * 8 + 4);
    float4 ka2 = *(const float4*)(ksum + h * 64 + 32 + quad * 8);
    float4 ka3 = *(const float4*)(ksum + h * 64 + 32 + quad * 8 + 4);
    float dq = x0.x * ka0.x + x0.y * ka0.y + x0.z * ka0.z + x0.w * ka0.w
             + x1.x * ka1.x + x1.y * ka1.y + x1.z * ka1.z + x1.w * ka1.w
             + x2.x * ka2.x + x2.y * ka2.y + x2.z * ka2.z + x2.w * ka2.w
             + x3.x * ka3.x + x3.y * ka3.y + x3.z * ka3.z + x3.w * ka3.w;
    dq += __shfl_xor(dq, 16, 64);
    dq += __shfl_xor(dq, 32, 64);
    float invd = 1.f / (dq * qsc + 1e-6f);
    x0.x *= qsc; x0.y *= qsc; x0.z *= qsc; x0.w *= qsc;
    x1.x *= qsc; x1.y *= qsc; x1.z *= qsc; x1.w *= qsc;
    x2.x *= qsc; x2.y *= qsc; x2.z *= qsc; x2.w *= qsc;
    x3.x *= qsc; x3.y *= qsc; x3.z *= qsc; x3.w *= qsc;
    bf16x8 qf[2];
    qf[0] = cvt8(x0, x1);
    qf[1] = cvt8(x2, x3);

    __syncthreads();                 // drains vmcnt: buf0 + KWt visible

    f32x4 Ol[4];
    #pragma unroll
    for (int dt = 0; dt < 4; dt++) Ol[dt] = (f32x4){0.f, 0.f, 0.f, 0.f};
    __builtin_amdgcn_s_setprio(1);
    #pragma unroll
    for (int dt = 0; dt < 4; dt++) {
        #pragma unroll
        for (int kc = 0; kc < 2; kc++) {
            int flat = (dt * 16 + l15) * 64 + kc * 32 + quad * 8;
            bf16x8 a = (dt < 2) ? *(const bf16x8*)&Kb[1][flat]
                                : *(const bf16x8*)&Vb[1][flat - 2048];
            Ol[dt] = __builtin_amdgcn_mfma_f32_16x16x32_bf16(a, qf[kc], Ol[dt], 0, 0, 0);
        }
    }
    __builtin_amdgcn_s_setprio(0);

    f32x4 O[4];
    #pragma unroll
    for (int dt = 0; dt < 4; dt++) O[dt] = (f32x4){0.f, 0.f, 0.f, 0.f};
    float l_i = 0.f;
    const f32x4 z = (f32x4){0.f, 0.f, 0.f, 0.f};
    const float EC = 1.44269504f * 0.125f;   // exact: 0.125*log2e, single rounding

    for (int ti = 0; ti < TSEL; ti++) {
        __syncthreads();              // B1: staging for ti complete
        int buf = ti & 1;
        if (ti + 1 < TSEL) {
            size_t base = (size_t)(h * 256 + lut_s[ti + 1]) * 2048;
            load_lds16(kswz + base + t * 8, &Kb[buf ^ 1][t * 8]);
            load_lds16(vswz + base + t * 8, &Vb[buf ^ 1][t * 8]);
        }
        int r0 = l15, r1 = 16 + l15;
        bf16x8 a00 = *(const bf16x8*)&Kb[buf][(r0 * 8 + (quad ^ (r0 & 7))) * 8];
        bf16x8 a01 = *(const bf16x8*)&Kb[buf][(r0 * 8 + ((4 + quad) ^ (r0 & 7))) * 8];
        bf16x8 a10 = *(const bf16x8*)&Kb[buf][(r1 * 8 + (quad ^ (r1 & 7))) * 8];
        bf16x8 a11 = *(const bf16x8*)&Kb[buf][(r1 * 8 + ((4 + quad) ^ (r1 & 7))) * 8];
        __builtin_amdgcn_s_setprio(1);
        f32x4 s0 = __builtin_amdgcn_mfma_f32_16x16x32_bf16(a00, qa[0], z, 0, 0, 0);
        s0 = __builtin_amdgcn_mfma_f32_16x16x32_bf16(a01, qa[1], s0, 0, 0, 0);
        f32x4 s1 = __builtin_amdgcn_mfma_f32_16x16x32_bf16(a10, qa[0], z, 0, 0, 0);
        s1 = __builtin_amdgcn_mfma_f32_16x16x32_bf16(a11, qa[1], s1, 0, 0, 0);
        __builtin_amdgcn_s_setprio(0);

        float p0[4], p1[4];
        float lsum = 0.f;
        #pragma unroll
        for (int r = 0; r < 4; r++) {
            p0[r] = exp2a(s0[r] * EC);
            p1[r] = exp2a(s1[r] * EC);
            lsum += p0[r] + p1[r];
        }
        lsum += __shfl_xor(lsum, 16, 64);
        lsum += __shfl_xor(lsum, 32, 64);
        l_i += lsum;

        uint2 pkA, pkB;
        pkA.x = cvtpk(p0[0], p0[1]); pkA.y = cvtpk(p0[2], p0[3]);
        pkB.x = cvtpk(p1[0], p1[1]); pkB.y = cvtpk(p1[2], p1[3]);
        *(uint2*)&Pl[w * 16 + l15][quad * 4] = pkA;
        *(uint2*)&Pl[w * 16 + l15][16 + quad * 4] = pkB;

        // B2: LDS-only barrier — async prefetch stays in flight
        asm volatile("s_waitcnt lgkmcnt(0)\n\ts_barrier" ::: "memory");

        bf16x8 pb = *(const bf16x8*)&Pl[w * 16 + l15][quad * 8];
        __builtin_amdgcn_s_setprio(1);
        #pragma unroll
        for (int dt = 0; dt < 4; dt++) {
            int d = dt * 16 + l15;
            bf16x8 va = *(const bf16x8*)&Vb[buf][(d * 4 + (quad ^ ((d >> 1) & 3))) * 8];
            O[dt] = __builtin_amdgcn_mfma_f32_16x16x32_bf16(va, pb, O[dt], 0, 0, 0);
        }
        __builtin_amdgcn_s_setprio(0);
    }

    float inv = 1.f / l_i;
    float* dst = out + (size_t)(m * 64 + w * 16 + l15) * HD + h * 64;
    #pragma unroll
    for (int dt = 0; dt < 4; dt++) {
        float4 bv = *(const float4*)(bproj + dt * 16 + quad * 4);
        float4 o;
        o.x = O[dt][0] * inv + Ol[dt][0] * invd + bv.x;
        o.y = O[dt][1] * inv + Ol[dt][1] * invd + bv.y;
        o.z = O[dt][2] * inv + Ol[dt][2] * invd + bv.z;
        o.w = O[dt][3] * inv + Ol[dt][3] * invd + bv.w;
        *(float4*)(dst + dt * 16 + quad * 4) = o;
    }
}

extern "C" void kernel_launch(void* const* d_in, const int* in_sizes, int n_in,
                              void* d_out, int out_size, void* d_ws, size_t ws_size,
                              hipStream_t stream) {
    const float* q  = (const float*)d_in[0];
    const float* k  = (const float*)d_in[1];
    const float* v  = (const float*)d_in[2];
    const float* W  = (const float*)d_in[3];
    const float* bp = (const float*)d_in[4];
    float* out = (float*)d_out;
    float* ws = (float*)d_ws;

    float* kvpart = ws + OFF_KVPART;
    float* ksum   = ws + OFF_KSUM;
    float* pk     = ws + OFF_PK;
    short* kwt    = (short*)(ws + OFF_KWT);
    short* kswz   = (short*)(ws + OFF_KSWZ);
    short* vswz   = kswz + (size_t)16 * 256 * 2048;
    int*   lut    = (int*)(ws + OFF_LUT);  // overlays kvpart; written after kw_mul consumed it

    hipMemsetAsync(ws, 0, OFF_ZEND * sizeof(float), stream);
    prep_kv<<<4096, 256, 0, stream>>>(k, v, kswz, vswz, pk);
    lin_kv<<<2048, 256, 0, stream>>>(k, v, kvpart, ksum);
    kw_mul<<<64, 256, 0, stream>>>(kvpart, W, kwt);
    score_topk<<<2048, 256, 0, stream>>>(q, pk, lut);
    sparse_attn_mfma<<<2048, 256, 0, stream>>>(q, kswz, vswz, lut, kwt, ksum, bp, out);
}

// Round 3
// 286.031 us; speedup vs baseline: 1.2538x; 1.2538x over previous
//
#include <hip/hip_runtime.h>
#include <math.h>

#define SEQL 8192
#define NH 16
#define HD 1024           // NH * 64
#define TSEL 25

// ---- workspace layout (float offsets) ----
#define OFF_KVPART 0                         // 4*16*4096 = 262144 (zeroed)
#define OFF_KSUM   262144                    // 1024 (zeroed)
#define OFF_ZEND   263168
#define OFF_PK     263168                    // 16*256*64 = 262144
#define OFF_KWT    525312                    // 16*4096 shorts = 32768 floats
#define OFF_KSWZ   558080                    // 16*256*2048 shorts
#define OFF_LUT    131072                    // overlays kvpart; written by score_topk AFTER kw_mul consumed kvpart

typedef __attribute__((ext_vector_type(8))) short bf16x8;
typedef __attribute__((ext_vector_type(4))) float f32x4;

static __device__ inline short f2bf(float f) {
    union { float f; unsigned u; } c; c.f = f;
    unsigned r = (c.u + 0x7FFFu + ((c.u >> 16) & 1u)) >> 16;
    return (short)r;
}
static __device__ inline bf16x8 cvt8(float4 a, float4 b) {
    bf16x8 r;
    r[0] = f2bf(a.x); r[1] = f2bf(a.y); r[2] = f2bf(a.z); r[3] = f2bf(a.w);
    r[4] = f2bf(b.x); r[5] = f2bf(b.y); r[6] = f2bf(b.z); r[7] = f2bf(b.w);
    return r;
}
static __device__ inline unsigned cvtpk(float a, float b) {
    unsigned r;
    asm("v_cvt_pk_bf16_f32 %0, %1, %2" : "=v"(r) : "v"(a), "v"(b));
    return r;
}
static __device__ inline float exp2a(float x) {
#if __has_builtin(__builtin_amdgcn_exp2f)
    return __builtin_amdgcn_exp2f(x);
#else
    float r; asm("v_exp_f32 %0, %1" : "=v"(r) : "v"(x)); return r;
#endif
}
static __device__ inline void load_lds16(const void* g, void* l) {
    __builtin_amdgcn_global_load_lds((const __attribute__((address_space(1))) unsigned int*)g,
                                     (__attribute__((address_space(3))) unsigned int*)l,
                                     16, 0, 0);
}

// K1: pre-pass — per (h,n): K tile -> bf16 swizzled; V tile -> V^T bf16 swizzled;
// fused pooled_k. UNCHANGED (keeps pk summation order bit-identical -> topk stable).
__global__ __launch_bounds__(256) void prep_kv(const float* __restrict__ k,
                                               const float* __restrict__ v,
                                               short* __restrict__ kswz,
                                               short* __restrict__ vswz,
                                               float* __restrict__ pk) {
    __shared__ float pcol[4][64];
    int b = blockIdx.x;            // h*256 + n
    int h = b >> 8, n = b & 255;
    int t = threadIdx.x;
    {   // K: thread = (r = t>>3, ch = t&7)
        int r = t >> 3, ch = t & 7;
        const float* src = k + (size_t)(n * 32 + r) * HD + h * 64 + ch * 8;
        float4 f0 = *(const float4*)src, f1 = *(const float4*)(src + 4);
        int f = r * 8 + (ch ^ (r & 7));
        *(bf16x8*)(kswz + (size_t)b * 2048 + f * 8) = cvt8(f0, f1);
        float s[8] = { f0.x, f0.y, f0.z, f0.w, f1.x, f1.y, f1.z, f1.w };
        #pragma unroll
        for (int j = 0; j < 8; j++) {
            s[j] += __shfl_xor(s[j], 8, 64);
            s[j] += __shfl_xor(s[j], 16, 64);
            s[j] += __shfl_xor(s[j], 32, 64);
        }
        if ((t & 63) < 8) {
            #pragma unroll
            for (int j = 0; j < 8; j++) pcol[t >> 6][(t & 7) * 8 + j] = s[j];
        }
    }
    {   // V^T
        int c = t >> 6, d = t & 63;
        const float* src = v + (size_t)(n * 32 + c * 8) * HD + h * 64 + d;
        bf16x8 val;
        #pragma unroll
        for (int j = 0; j < 8; j++) val[j] = f2bf(src[(size_t)j * HD]);
        int f = d * 4 + (c ^ ((d >> 1) & 3));
        *(bf16x8*)(vswz + (size_t)b * 2048 + f * 8) = val;
    }
    __syncthreads();
    if (t < 64)
        pk[(size_t)b * 64 + t] =
            (pcol[0][t] + pcol[1][t] + pcol[2][t] + pcol[3][t]) * (1.f / 32.f);
}

// K3: pooled_q fused (threads t<64 run pool_q's EXACT serial loop -> bit-identical),
// then scores (f64 accum, same order) + top-25 rank select, ballot compaction.
__global__ __launch_bounds__(256) void score_topk(const float* __restrict__ q,
                                                  const float* __restrict__ pk,
                                                  int* __restrict__ lut) {
    __shared__ __align__(16) float pq_s[64];
    __shared__ __align__(16) float s_s[256];
    __shared__ int wcnt[4];
    int b = blockIdx.x;            // h*128 + m
    int h = b >> 7, m = b & 127;
    int t = threadIdx.x;
    int lane = t & 63, w = t >> 6;
    if (t < 64) {
        const float* base = q + (size_t)m * 64 * HD + h * 64 + t;
        float s = 0.f;
        #pragma unroll 8
        for (int r = 0; r < 64; r++) s += base[(size_t)r * HD];
        pq_s[t] = s * (1.f / 64.f);
    }
    __syncthreads();
    const float* kr = pk + ((size_t)h * 256 + t) * 64;
    double acc = 0.0;
    #pragma unroll 8
    for (int d = 0; d < 64; d++) acc += (double)pq_s[d] * (double)kr[d];
    float sc = (float)acc;
    s_s[t] = sc;
    __syncthreads();
    int cnt = 0;
    float si = sc;
    #pragma unroll 4
    for (int j4 = 0; j4 < 64; j4++) {
        float4 sv = *(const float4*)&s_s[j4 * 4];
        int j = j4 * 4;
        cnt += (sv.x > si) || (sv.x == si && (j + 0) < t);
        cnt += (sv.y > si) || (sv.y == si && (j + 1) < t);
        cnt += (sv.z > si) || (sv.z == si && (j + 2) < t);
        cnt += (sv.w > si) || (sv.w == si && (j + 3) < t);
    }
    bool sel = cnt < TSEL;
    unsigned long long bal = __ballot(sel);
    if (lane == 0) wcnt[w] = __popcll(bal);
    __syncthreads();
    if (sel) {
        int off = __popcll(bal & ((1ull << lane) - 1ull));
        for (int i = 0; i < w; i++) off += wcnt[i];
        lut[(size_t)b * TSEL + off] = t;
    }
}

// K4: kvpart += k_fm^T v. 512 blocks (h x 32 superchunks of 256 rows), 4 phases
// of 64 rows each with double-buffered LDS + register prefetch of next phase
// (one barrier per phase, no pipeline bubble). Accumulator carried in registers
// across phases -> ONE atomic write-out per block (2.1M atomics vs 8.4M; this is
// what governed rounds 1-2: dur tracked atomic WRITE_SIZE). Inner loop: 4d x 4e
// tile, 2 per-lane ds_read_b128 per row. Softmax sequence identical to round 0.
__global__ __launch_bounds__(256) void lin_kv(const float* __restrict__ k,
                                              const float* __restrict__ v,
                                              float* __restrict__ kvpart,
                                              float* __restrict__ ksum) {
    __shared__ __align__(16) float kf[2][64][68];
    __shared__ __align__(16) float vv[2][64][68];
    int b = blockIdx.x;            // h*32 + sc
    int h = b >> 5, sc = b & 31;
    int l0 = sc * 256;
    int t = threadIdx.x;
    int lane = t & 63, w = t >> 6;
    int row = t >> 2, c16 = (t & 3) * 16;
    int d0 = (lane >> 4) * 4 + w * 16;   // quad -> d, wave -> d-block (broadcast reads)
    int e0 = (lane & 15) * 4;            // lane -> e (2-way max on reads)
    float acc[16];
    #pragma unroll
    for (int i = 0; i < 16; i++) acc[i] = 0.f;
    float ks_acc = 0.f;

    const float* kbase = k + (size_t)(l0 + row) * HD + h * 64 + c16;
    const float* vbase = v + (size_t)(l0 + row) * HD + h * 64 + c16;
    float4 X0 = *(const float4*)(kbase);
    float4 X1 = *(const float4*)(kbase + 4);
    float4 X2 = *(const float4*)(kbase + 8);
    float4 X3 = *(const float4*)(kbase + 12);
    float4 V0 = *(const float4*)(vbase);
    float4 V1 = *(const float4*)(vbase + 4);
    float4 V2 = *(const float4*)(vbase + 8);
    float4 V3 = *(const float4*)(vbase + 12);

    #pragma unroll
    for (int ph = 0; ph < 4; ph++) {
        int buf = ph & 1;
        {   // V tile -> LDS
            float4* vd = (float4*)&vv[buf][row][c16];
            vd[0] = V0; vd[1] = V1; vd[2] = V2; vd[3] = V3;
        }
        // row softmax (sequence identical to rounds 0-2 -> bit-identical)
        float mx = fmaxf(fmaxf(fmaxf(X0.x, X0.y), fmaxf(X0.z, X0.w)),
                         fmaxf(fmaxf(X1.x, X1.y), fmaxf(X1.z, X1.w)));
        mx = fmaxf(mx, fmaxf(fmaxf(fmaxf(X2.x, X2.y), fmaxf(X2.z, X2.w)),
                             fmaxf(fmaxf(X3.x, X3.y), fmaxf(X3.z, X3.w))));
        mx = fmaxf(mx, __shfl_xor(mx, 1, 64));
        mx = fmaxf(mx, __shfl_xor(mx, 2, 64));
        X0.x = __expf(X0.x - mx); X0.y = __expf(X0.y - mx); X0.z = __expf(X0.z - mx); X0.w = __expf(X0.w - mx);
        X1.x = __expf(X1.x - mx); X1.y = __expf(X1.y - mx); X1.z = __expf(X1.z - mx); X1.w = __expf(X1.w - mx);
        X2.x = __expf(X2.x - mx); X2.y = __expf(X2.y - mx); X2.z = __expf(X2.z - mx); X2.w = __expf(X2.w - mx);
        X3.x = __expf(X3.x - mx); X3.y = __expf(X3.y - mx); X3.z = __expf(X3.z - mx); X3.w = __expf(X3.w - mx);
        float sm = (X0.x + X0.y + X0.z + X0.w) + (X1.x + X1.y + X1.z + X1.w)
                 + (X2.x + X2.y + X2.z + X2.w) + (X3.x + X3.y + X3.z + X3.w);
        sm += __shfl_xor(sm, 1, 64);
        sm += __shfl_xor(sm, 2, 64);
        float inv = 1.f / sm;
        X0.x *= inv; X0.y *= inv; X0.z *= inv; X0.w *= inv;
        X1.x *= inv; X1.y *= inv; X1.z *= inv; X1.w *= inv;
        X2.x *= inv; X2.y *= inv; X2.z *= inv; X2.w *= inv;
        X3.x *= inv; X3.y *= inv; X3.z *= inv; X3.w *= inv;
        {   // k_fm tile -> LDS
            float4* kd = (float4*)&kf[buf][row][c16];
            kd[0] = X0; kd[1] = X1; kd[2] = X2; kd[3] = X3;
        }
        // prefetch next phase into registers (HBM latency hides under inner loop)
        if (ph < 3) {
            const float* kn = kbase + (size_t)(ph + 1) * 64 * HD;
            const float* vn = vbase + (size_t)(ph + 1) * 64 * HD;
            X0 = *(const float4*)(kn);     X1 = *(const float4*)(kn + 4);
            X2 = *(const float4*)(kn + 8); X3 = *(const float4*)(kn + 12);
            V0 = *(const float4*)(vn);     V1 = *(const float4*)(vn + 4);
            V2 = *(const float4*)(vn + 8); V3 = *(const float4*)(vn + 12);
        }
        __syncthreads();
        #pragma unroll 8
        for (int l = 0; l < 64; l++) {
            float4 kd = *(const float4*)&kf[buf][l][d0];
            float4 ve = *(const float4*)&vv[buf][l][e0];
            acc[0]  += kd.x * ve.x; acc[1]  += kd.x * ve.y; acc[2]  += kd.x * ve.z; acc[3]  += kd.x * ve.w;
            acc[4]  += kd.y * ve.x; acc[5]  += kd.y * ve.y; acc[6]  += kd.y * ve.z; acc[7]  += kd.y * ve.w;
            acc[8]  += kd.z * ve.x; acc[9]  += kd.z * ve.y; acc[10] += kd.z * ve.z; acc[11] += kd.z * ve.w;
            acc[12] += kd.w * ve.x; acc[13] += kd.w * ve.y; acc[14] += kd.w * ve.z; acc[15] += kd.w * ve.w;
        }
        if (t < 64) {
            float s = 0.f;
            #pragma unroll 8
            for (int l = 0; l < 64; l++) s += kf[buf][l][t];
            ks_acc += s;
        }
        // next phase writes the OTHER buffer; this buffer is rewritten only at
        // ph+2, after the ph+1 barrier has confirmed all reads here finished.
    }
    float* dst = kvpart + ((size_t)(sc & 3) * 16 + h) * 4096;
    #pragma unroll
    for (int i = 0; i < 4; i++)
        #pragma unroll
        for (int j = 0; j < 4; j++)
            atomicAdd(&dst[(d0 + i) * 64 + e0 + j], acc[i * 4 + j]);
    if (t < 64) atomicAdd(&ksum[h * 64 + t], ks_acc);
}

// K5: reduce partials + KWt = kvsum · W^T (bf16, transposed layout).
// 64 blocks (h x d-quarter); float4 dots; conflict-aware operand mapping.
__global__ __launch_bounds__(256) void kw_mul(const float* __restrict__ kvpart,
                                              const float* __restrict__ W,
                                              short* __restrict__ kwt) {
    __shared__ __align__(16) float kv[16][68];
    __shared__ __align__(16) float wsm[64][68];
    int h = blockIdx.x >> 2, dq = blockIdx.x & 3;
    int t = threadIdx.x;
    for (int i = t; i < 1024; i += 256) {
        int dl = i >> 6, e = i & 63;
        float s = 0.f;
        #pragma unroll
        for (int p = 0; p < 4; p++)
            s += kvpart[((size_t)p * 16 + h) * 4096 + (dq * 16 + dl) * 64 + e];
        kv[dl][e] = s;
    }
    for (int i = t; i < 4096; i += 256) wsm[i >> 6][i & 63] = W[i];
    __syncthreads();
    int lane = t & 63, wi = t >> 6;
    int dl = lane & 15;
    int db = wi * 16 + (lane >> 4) * 4;
    #pragma unroll
    for (int j = 0; j < 4; j++) {
        int dd = db + j;
        float a = 0.f;
        #pragma unroll
        for (int e4 = 0; e4 < 16; e4++) {
            float4 kq = *(const float4*)&kv[dl][e4 * 4];
            float4 wq = *(const float4*)&wsm[dd][e4 * 4];
            a += kq.x * wq.x + kq.y * wq.y + kq.z * wq.z + kq.w * wq.w;
        }
        kwt[(size_t)h * 4096 + dd * 64 + dq * 16 + dl] = f2bf(a);
    }
}

// K6: fused block-sparse attention + linear branch (unchanged from round 1:
// cvt_pk P-pack, ds_write_b64, exp2-folded constant, setprio around MFMA).
__global__ __launch_bounds__(256) void sparse_attn_mfma(const float* __restrict__ q,
                                                        const short* __restrict__ kswz,
                                                        const short* __restrict__ vswz,
                                                        const int* __restrict__ lut,
                                                        const short* __restrict__ kwt,
                                                        const float* __restrict__ ksum,
                                                        const float* __restrict__ bproj,
                                                        float* __restrict__ out) {
    __shared__ __align__(16) short Kb[2][2048];
    __shared__ __align__(16) short Vb[2][2048];
    __shared__ __align__(16) short Pl[64][40];
    __shared__ int lut_s[TSEL];

    int b = blockIdx.x;
    int x = b & 7, jj = b >> 3;
    int h = x * 2 + (jj >> 7);       // XCD-affine
    int m = jj & 127;
    int t = threadIdx.x;
    int lane = t & 63, w = t >> 6;
    int l15 = lane & 15, quad = lane >> 4;

    if (t < TSEL) lut_s[t] = lut[(size_t)(h * 128 + m) * TSEL + t];
    __syncthreads();

    {
        size_t base = (size_t)(h * 256 + lut_s[0]) * 2048;
        load_lds16(kswz + base + t * 8, &Kb[0][t * 8]);
        load_lds16(vswz + base + t * 8, &Vb[0][t * 8]);
        load_lds16(kwt + (size_t)h * 4096 + t * 8, &Kb[1][t * 8]);
        load_lds16(kwt + (size_t)h * 4096 + 2048 + t * 8, &Vb[1][t * 8]);
    }

    const float* qrow = q + (size_t)(m * 64 + w * 16 + l15) * HD + h * 64;
    float4 x0 = *(const float4*)(qrow + quad * 8);
    float4 x1 = *(const float4*)(qrow + quad * 8 + 4);
    float4 x2 = *(const float4*)(qrow + 32 + quad * 8);
    float4 x3 = *(const float4*)(qrow + 32 + quad * 8 + 4);
    bf16x8 qa[2];
    qa[0] = cvt8(x0, x1);
    qa[1] = cvt8(x2, x3);

    float mx = fmaxf(fmaxf(fmaxf(x0.x, x0.y), fmaxf(x0.z, x0.w)),
                     fmaxf(fmaxf(x1.x, x1.y), fmaxf(x1.z, x1.w)));
    mx = fmaxf(mx, fmaxf(fmaxf(fmaxf(x2.x, x2.y), fmaxf(x2.z, x2.w)),
                         fmaxf(fmaxf(x3.x, x3.y), fmaxf(x3.z, x3.w))));
    mx = fmaxf(mx, __shfl_xor(mx, 16, 64));
    mx = fmaxf(mx, __shfl_xor(mx, 32, 64));
    x0.x = __expf(x0.x - mx); x0.y = __expf(x0.y - mx); x0.z = __expf(x0.z - mx); x0.w = __expf(x0.w - mx);
    x1.x = __expf(x1.x - mx); x1.y = __expf(x1.y - mx); x1.z = __expf(x1.z - mx); x1.w = __expf(x1.w - mx);
    x2.x = __expf(x2.x - mx); x2.y = __expf(x2.y - mx); x2.z = __expf(x2.z - mx); x2.w = __expf(x2.w - mx);
    x3.x = __expf(x3.x - mx); x3.y = __expf(x3.y - mx); x3.z = __expf(x3.z - mx); x3.w = __expf(x3.w - mx);
    float sm = (x0.x + x0.y + x0.z + x0.w) + (x1.x + x1.y + x1.z + x1.w)
             + (x2.x + x2.y + x2.z + x2.w) + (x3.x + x3.y + x3.z + x3.w);
    sm += __shfl_xor(sm, 16, 64);
    sm += __shfl_xor(sm, 32, 64);
    float qsc = 1.f / sm;
    float4 ka0 = *(const float4*)(ksum + h * 64 + quad * 8);
    float4 ka1 = *(const float4*)(ksum + h * 64 + quad * 8 + 4);
    float4 ka2 = *(const float4*)(ksum + h * 64 + 32 + quad * 8);
    float4 ka3 = *(const float4*)(ksum + h * 64 + 32 + quad * 8 + 4);
    float dq = x0.x * ka0.x + x0.y * ka0.y + x0.z * ka0.z + x0.w * ka0.w
             + x1.x * ka1.x + x1.y * ka1.y + x1.z * ka1.z + x1.w * ka1.w
             + x2.x * ka2.x + x2.y * ka2.y + x2.z * ka2.z + x2.w * ka2.w
             + x3.x * ka3.x + x3.y * ka3.y + x3.z * ka3.z + x3.w * ka3.w;
    dq += __shfl_xor(dq, 16, 64);
    dq += __shfl_xor(dq, 32, 64);
    float invd = 1.f / (dq * qsc + 1e-6f);
    x0.x *= qsc; x0.y *= qsc; x0.z *= qsc; x0.w *= qsc;
    x1.x *= qsc; x1.y *= qsc; x1.z *= qsc; x1.w *= qsc;
    x2.x *= qsc; x2.y *= qsc; x2.z *= qsc; x2.w *= qsc;
    x3.x *= qsc; x3.y *= qsc; x3.z *= qsc; x3.w *= qsc;
    bf16x8 qf[2];
    qf[0] = cvt8(x0, x1);
    qf[1] = cvt8(x2, x3);

    __syncthreads();                 // drains vmcnt: buf0 + KWt visible

    f32x4 Ol[4];
    #pragma unroll
    for (int dt = 0; dt < 4; dt++) Ol[dt] = (f32x4){0.f, 0.f, 0.f, 0.f};
    __builtin_amdgcn_s_setprio(1);
    #pragma unroll
    for (int dt = 0; dt < 4; dt++) {
        #pragma unroll
        for (int kc = 0; kc < 2; kc++) {
            int flat = (dt * 16 + l15) * 64 + kc * 32 + quad * 8;
            bf16x8 a = (dt < 2) ? *(const bf16x8*)&Kb[1][flat]
                                : *(const bf16x8*)&Vb[1][flat - 2048];
            Ol[dt] = __builtin_amdgcn_mfma_f32_16x16x32_bf16(a, qf[kc], Ol[dt], 0, 0, 0);
        }
    }
    __builtin_amdgcn_s_setprio(0);

    f32x4 O[4];
    #pragma unroll
    for (int dt = 0; dt < 4; dt++) O[dt] = (f32x4){0.f, 0.f, 0.f, 0.f};
    float l_i = 0.f;
    const f32x4 z = (f32x4){0.f, 0.f, 0.f, 0.f};
    const float EC = 1.44269504f * 0.125f;   // exact: 0.125*log2e, single rounding

    for (int ti = 0; ti < TSEL; ti++) {
        __syncthreads();              // B1: staging for ti complete
        int buf = ti & 1;
        if (ti + 1 < TSEL) {
            size_t base = (size_t)(h * 256 + lut_s[ti + 1]) * 2048;
            load_lds16(kswz + base + t * 8, &Kb[buf ^ 1][t * 8]);
            load_lds16(vswz + base + t * 8, &Vb[buf ^ 1][t * 8]);
        }
        int r0 = l15, r1 = 16 + l15;
        bf16x8 a00 = *(const bf16x8*)&Kb[buf][(r0 * 8 + (quad ^ (r0 & 7))) * 8];
        bf16x8 a01 = *(const bf16x8*)&Kb[buf][(r0 * 8 + ((4 + quad) ^ (r0 & 7))) * 8];
        bf16x8 a10 = *(const bf16x8*)&Kb[buf][(r1 * 8 + (quad ^ (r1 & 7))) * 8];
        bf16x8 a11 = *(const bf16x8*)&Kb[buf][(r1 * 8 + ((4 + quad) ^ (r1 & 7))) * 8];
        __builtin_amdgcn_s_setprio(1);
        f32x4 s0 = __builtin_amdgcn_mfma_f32_16x16x32_bf16(a00, qa[0], z, 0, 0, 0);
        s0 = __builtin_amdgcn_mfma_f32_16x16x32_bf16(a01, qa[1], s0, 0, 0, 0);
        f32x4 s1 = __builtin_amdgcn_mfma_f32_16x16x32_bf16(a10, qa[0], z, 0, 0, 0);
        s1 = __builtin_amdgcn_mfma_f32_16x16x32_bf16(a11, qa[1], s1, 0, 0, 0);
        __builtin_amdgcn_s_setprio(0);

        float p0[4], p1[4];
        float lsum = 0.f;
        #pragma unroll
        for (int r = 0; r < 4; r++) {
            p0[r] = exp2a(s0[r] * EC);
            p1[r] = exp2a(s1[r] * EC);
            lsum += p0[r] + p1[r];
        }
        lsum += __shfl_xor(lsum, 16, 64);
        lsum += __shfl_xor(lsum, 32, 64);
        l_i += lsum;

        uint2 pkA, pkB;
        pkA.x = cvtpk(p0[0], p0[1]); pkA.y = cvtpk(p0[2], p0[3]);
        pkB.x = cvtpk(p1[0], p1[1]); pkB.y = cvtpk(p1[2], p1[3]);
        *(uint2*)&Pl[w * 16 + l15][quad * 4] = pkA;
        *(uint2*)&Pl[w * 16 + l15][16 + quad * 4] = pkB;

        // B2: LDS-only barrier — async prefetch stays in flight
        asm volatile("s_waitcnt lgkmcnt(0)\n\ts_barrier" ::: "memory");

        bf16x8 pb = *(const bf16x8*)&Pl[w * 16 + l15][quad * 8];
        __builtin_amdgcn_s_setprio(1);
        #pragma unroll
        for (int dt = 0; dt < 4; dt++) {
            int d = dt * 16 + l15;
            bf16x8 va = *(const bf16x8*)&Vb[buf][(d * 4 + (quad ^ ((d >> 1) & 3))) * 8];
            O[dt] = __builtin_amdgcn_mfma_f32_16x16x32_bf16(va, pb, O[dt], 0, 0, 0);
        }
        __builtin_amdgcn_s_setprio(0);
    }

    float inv = 1.f / l_i;
    float* dst = out + (size_t)(m * 64 + w * 16 + l15) * HD + h * 64;
    #pragma unroll
    for (int dt = 0; dt < 4; dt++) {
        float4 bv = *(const float4*)(bproj + dt * 16 + quad * 4);
        float4 o;
        o.x = O[dt][0] * inv + Ol[dt][0] * invd + bv.x;
        o.y = O[dt][1] * inv + Ol[dt][1] * invd + bv.y;
        o.z = O[dt][2] * inv + Ol[dt][2] * invd + bv.z;
        o.w = O[dt][3] * inv + Ol[dt][3] * invd + bv.w;
        *(float4*)(dst + dt * 16 + quad * 4) = o;
    }
}

extern "C" void kernel_launch(void* const* d_in, const int* in_sizes, int n_in,
                              void* d_out, int out_size, void* d_ws, size_t ws_size,
                              hipStream_t stream) {
    const float* q  = (const float*)d_in[0];
    const float* k  = (const float*)d_in[1];
    const float* v  = (const float*)d_in[2];
    const float* W  = (const float*)d_in[3];
    const float* bp = (const float*)d_in[4];
    float* out = (float*)d_out;
    float* ws = (float*)d_ws;

    float* kvpart = ws + OFF_KVPART;
    float* ksum   = ws + OFF_KSUM;
    float* pk     = ws + OFF_PK;
    short* kwt    = (short*)(ws + OFF_KWT);
    short* kswz   = (short*)(ws + OFF_KSWZ);
    short* vswz   = kswz + (size_t)16 * 256 * 2048;
    int*   lut    = (int*)(ws + OFF_LUT);  // overlays kvpart; written after kw_mul consumed it

    hipMemsetAsync(ws, 0, OFF_ZEND * sizeof(float), stream);
    prep_kv<<<4096, 256, 0, stream>>>(k, v, kswz, vswz, pk);
    lin_kv<<<512, 256, 0, stream>>>(k, v, kvpart, ksum);
    kw_mul<<<64, 256, 0, stream>>>(kvpart, W, kwt);
    score_topk<<<2048, 256, 0, stream>>>(q, pk, lut);
    sparse_attn_mfma<<<2048, 256, 0, stream>>>(q, kswz, vswz, lut, kwt, ksum, bp, out);
}

// Round 4
// 267.917 us; speedup vs baseline: 1.3386x; 1.0676x over previous
//
#include <hip/hip_runtime.h>
#include <math.h>

#define SEQL 8192
#define NH 16
#define HD 1024           // NH * 64
#define TSEL 25

// ---- workspace layout (float offsets) ----
#define OFF_KVPART 0                         // 4*16*4096 = 262144 (zeroed)
#define OFF_KSUM   262144                    // 1024 (zeroed)
#define OFF_ZEND   263168
#define OFF_PK     263168                    // 16*256*64 = 262144
#define OFF_KWT    525312                    // 16*4096 shorts = 32768 floats
#define OFF_KSWZ   558080                    // 16*256*2048 shorts
#define OFF_LUT    131072                    // overlays kvpart; written by score_topk AFTER kw_mul consumed kvpart

typedef __attribute__((ext_vector_type(8))) short bf16x8;
typedef __attribute__((ext_vector_type(4))) float f32x4;

static __device__ inline short f2bf(float f) {
    union { float f; unsigned u; } c; c.f = f;
    unsigned r = (c.u + 0x7FFFu + ((c.u >> 16) & 1u)) >> 16;
    return (short)r;
}
static __device__ inline bf16x8 cvt8(float4 a, float4 b) {
    bf16x8 r;
    r[0] = f2bf(a.x); r[1] = f2bf(a.y); r[2] = f2bf(a.z); r[3] = f2bf(a.w);
    r[4] = f2bf(b.x); r[5] = f2bf(b.y); r[6] = f2bf(b.z); r[7] = f2bf(b.w);
    return r;
}
static __device__ inline unsigned cvtpk(float a, float b) {
    unsigned r;
    asm("v_cvt_pk_bf16_f32 %0, %1, %2" : "=v"(r) : "v"(a), "v"(b));
    return r;
}
static __device__ inline float exp2a(float x) {
#if __has_builtin(__builtin_amdgcn_exp2f)
    return __builtin_amdgcn_exp2f(x);
#else
    float r; asm("v_exp_f32 %0, %1" : "=v"(r) : "v"(x)); return r;
#endif
}
static __device__ inline void load_lds16(const void* g, void* l) {
    __builtin_amdgcn_global_load_lds((const __attribute__((address_space(1))) unsigned int*)g,
                                     (__attribute__((address_space(3))) unsigned int*)l,
                                     16, 0, 0);
}

// K1: FUSED prep_kv + lin_kv. 512 blocks (h x 32 superchunks of 256 rows),
// 4 phases of 64 rows (= 2 prep-subtiles of 32), double-buffered LDS with
// register prefetch (round-3 lin_kv structure, which dropped off the top-5).
// Reads k/v ONCE (was twice across prep_kv+lin_kv = -67MB HBM).
// pk: per-subtile thread mapping, shfl tree, pcol combine replicated EXACTLY
// from prep_kv -> bit-identical -> topk stable. kswz from registers (same bits).
// vswz via LDS transpose-read of the raw-V stage (same f32 -> same bf16).
// Softmax sum-order differs from before: continuous o_l path only (safe; kvsum
// is already order-nondeterministic via atomics).
__global__ __launch_bounds__(256) void prep_lin(const float* __restrict__ k,
                                                const float* __restrict__ v,
                                                short* __restrict__ kswz,
                                                short* __restrict__ vswz,
                                                float* __restrict__ pk,
                                                float* __restrict__ kvpart,
                                                float* __restrict__ ksum) {
    __shared__ __align__(16) float kf[2][64][68];
    __shared__ __align__(16) float vv[2][64][68];
    __shared__ float pcol[2][2][4][64];     // [buf][sub][wave][d]
    int b = blockIdx.x;            // h*32 + sc
    int h = b >> 5, sc = b & 31;
    int t = threadIdx.x;
    int lane = t & 63, w = t >> 6;
    int r32 = t >> 3, ch = t & 7;          // prep mapping: 8 floats of one row
    int d0 = (lane >> 4) * 4 + w * 16;     // acc tile: quad -> d (broadcast reads)
    int e0 = (lane & 15) * 4;              // lane -> e (2-way, free)
    float acc[16];
    #pragma unroll
    for (int i = 0; i < 16; i++) acc[i] = 0.f;
    float ks_acc = 0.f;

    const float* kb_ = k + (size_t)(sc * 256 + r32) * HD + h * 64 + ch * 8;
    const float* vb_ = v + (size_t)(sc * 256 + r32) * HD + h * 64 + ch * 8;
    float4 K0a = *(const float4*)kb_;
    float4 K0b = *(const float4*)(kb_ + 4);
    float4 K1a = *(const float4*)(kb_ + (size_t)32 * HD);
    float4 K1b = *(const float4*)(kb_ + (size_t)32 * HD + 4);
    float4 V0a = *(const float4*)vb_;
    float4 V0b = *(const float4*)(vb_ + 4);
    float4 V1a = *(const float4*)(vb_ + (size_t)32 * HD);
    float4 V1b = *(const float4*)(vb_ + (size_t)32 * HD + 4);

    #pragma unroll
    for (int ph = 0; ph < 4; ph++) {
        int buf = ph & 1;
        int n0 = sc * 8 + ph * 2;          // global 32-row tile indices n0, n0+1
        // ---- write section ----
        {   // raw V stage
            *(float4*)&vv[buf][r32][ch * 8]          = V0a;
            *(float4*)&vv[buf][r32][ch * 8 + 4]      = V0b;
            *(float4*)&vv[buf][32 + r32][ch * 8]     = V1a;
            *(float4*)&vv[buf][32 + r32][ch * 8 + 4] = V1b;
        }
        {   // kswz (exact prep_kv bits, from registers)
            int f = r32 * 8 + (ch ^ (r32 & 7));
            *(bf16x8*)(kswz + (size_t)(h * 256 + n0) * 2048 + f * 8)     = cvt8(K0a, K0b);
            *(bf16x8*)(kswz + (size_t)(h * 256 + n0 + 1) * 2048 + f * 8) = cvt8(K1a, K1b);
        }
        {   // pk partial trees (EXACT prep_kv order, per subtile)
            float s_[8] = { K0a.x, K0a.y, K0a.z, K0a.w, K0b.x, K0b.y, K0b.z, K0b.w };
            #pragma unroll
            for (int j = 0; j < 8; j++) {
                s_[j] += __shfl_xor(s_[j], 8, 64);
                s_[j] += __shfl_xor(s_[j], 16, 64);
                s_[j] += __shfl_xor(s_[j], 32, 64);
            }
            if (lane < 8) {
                #pragma unroll
                for (int j = 0; j < 8; j++) pcol[buf][0][w][(t & 7) * 8 + j] = s_[j];
            }
            float s1_[8] = { K1a.x, K1a.y, K1a.z, K1a.w, K1b.x, K1b.y, K1b.z, K1b.w };
            #pragma unroll
            for (int j = 0; j < 8; j++) {
                s1_[j] += __shfl_xor(s1_[j], 8, 64);
                s1_[j] += __shfl_xor(s1_[j], 16, 64);
                s1_[j] += __shfl_xor(s1_[j], 32, 64);
            }
            if (lane < 8) {
                #pragma unroll
                for (int j = 0; j < 8; j++) pcol[buf][1][w][(t & 7) * 8 + j] = s1_[j];
            }
        }
        {   // row softmax subtile 0 (8 lanes/row; exact max, continuous-path sum)
            float mx = fmaxf(fmaxf(fmaxf(K0a.x, K0a.y), fmaxf(K0a.z, K0a.w)),
                             fmaxf(fmaxf(K0b.x, K0b.y), fmaxf(K0b.z, K0b.w)));
            mx = fmaxf(mx, __shfl_xor(mx, 1, 64));
            mx = fmaxf(mx, __shfl_xor(mx, 2, 64));
            mx = fmaxf(mx, __shfl_xor(mx, 4, 64));
            float4 Fa, Fb;
            Fa.x = __expf(K0a.x - mx); Fa.y = __expf(K0a.y - mx);
            Fa.z = __expf(K0a.z - mx); Fa.w = __expf(K0a.w - mx);
            Fb.x = __expf(K0b.x - mx); Fb.y = __expf(K0b.y - mx);
            Fb.z = __expf(K0b.z - mx); Fb.w = __expf(K0b.w - mx);
            float sm = (Fa.x + Fa.y + Fa.z + Fa.w) + (Fb.x + Fb.y + Fb.z + Fb.w);
            sm += __shfl_xor(sm, 1, 64);
            sm += __shfl_xor(sm, 2, 64);
            sm += __shfl_xor(sm, 4, 64);
            float inv = 1.f / sm;
            Fa.x *= inv; Fa.y *= inv; Fa.z *= inv; Fa.w *= inv;
            Fb.x *= inv; Fb.y *= inv; Fb.z *= inv; Fb.w *= inv;
            *(float4*)&kf[buf][r32][ch * 8]     = Fa;
            *(float4*)&kf[buf][r32][ch * 8 + 4] = Fb;
        }
        {   // row softmax subtile 1
            float mx = fmaxf(fmaxf(fmaxf(K1a.x, K1a.y), fmaxf(K1a.z, K1a.w)),
                             fmaxf(fmaxf(K1b.x, K1b.y), fmaxf(K1b.z, K1b.w)));
            mx = fmaxf(mx, __shfl_xor(mx, 1, 64));
            mx = fmaxf(mx, __shfl_xor(mx, 2, 64));
            mx = fmaxf(mx, __shfl_xor(mx, 4, 64));
            float4 Fa, Fb;
            Fa.x = __expf(K1a.x - mx); Fa.y = __expf(K1a.y - mx);
            Fa.z = __expf(K1a.z - mx); Fa.w = __expf(K1a.w - mx);
            Fb.x = __expf(K1b.x - mx); Fb.y = __expf(K1b.y - mx);
            Fb.z = __expf(K1b.z - mx); Fb.w = __expf(K1b.w - mx);
            float sm = (Fa.x + Fa.y + Fa.z + Fa.w) + (Fb.x + Fb.y + Fb.z + Fb.w);
            sm += __shfl_xor(sm, 1, 64);
            sm += __shfl_xor(sm, 2, 64);
            sm += __shfl_xor(sm, 4, 64);
            float inv = 1.f / sm;
            Fa.x *= inv; Fa.y *= inv; Fa.z *= inv; Fa.w *= inv;
            Fb.x *= inv; Fb.y *= inv; Fb.z *= inv; Fb.w *= inv;
            *(float4*)&kf[buf][32 + r32][ch * 8]     = Fa;
            *(float4*)&kf[buf][32 + r32][ch * 8 + 4] = Fb;
        }
        // register prefetch of next phase (HBM latency hides under read section)
        if (ph < 3) {
            const float* kn = kb_ + (size_t)(ph + 1) * 64 * HD;
            const float* vn = vb_ + (size_t)(ph + 1) * 64 * HD;
            K0a = *(const float4*)kn;
            K0b = *(const float4*)(kn + 4);
            K1a = *(const float4*)(kn + (size_t)32 * HD);
            K1b = *(const float4*)(kn + (size_t)32 * HD + 4);
            V0a = *(const float4*)vn;
            V0b = *(const float4*)(vn + 4);
            V1a = *(const float4*)(vn + (size_t)32 * HD);
            V1b = *(const float4*)(vn + (size_t)32 * HD + 4);
        }
        __syncthreads();
        // ---- read section ----
        if (t < 128) {   // pk combine (exact prep_kv expression per subtile)
            int s = t >> 6, d = t & 63;
            pk[(size_t)(h * 256 + n0 + s) * 64 + d] =
                (pcol[buf][s][0][d] + pcol[buf][s][1][d] + pcol[buf][s][2][d] + pcol[buf][s][3][d])
                * (1.f / 32.f);
        }
        {   // vswz: transpose-read raw V from LDS (conflict-free: lanes read consecutive d)
            int c = w, d = lane;
            #pragma unroll
            for (int s = 0; s < 2; s++) {
                bf16x8 val;
                #pragma unroll
                for (int j = 0; j < 8; j++) val[j] = f2bf(vv[buf][s * 32 + c * 8 + j][d]);
                int f = d * 4 + (c ^ ((d >> 1) & 3));
                *(bf16x8*)(vswz + (size_t)(h * 256 + n0 + s) * 2048 + f * 8) = val;
            }
        }
        #pragma unroll 8
        for (int l = 0; l < 64; l++) {
            float4 kd = *(const float4*)&kf[buf][l][d0];
            float4 ve = *(const float4*)&vv[buf][l][e0];
            acc[0]  += kd.x * ve.x; acc[1]  += kd.x * ve.y; acc[2]  += kd.x * ve.z; acc[3]  += kd.x * ve.w;
            acc[4]  += kd.y * ve.x; acc[5]  += kd.y * ve.y; acc[6]  += kd.y * ve.z; acc[7]  += kd.y * ve.w;
            acc[8]  += kd.z * ve.x; acc[9]  += kd.z * ve.y; acc[10] += kd.z * ve.z; acc[11] += kd.z * ve.w;
            acc[12] += kd.w * ve.x; acc[13] += kd.w * ve.y; acc[14] += kd.w * ve.z; acc[15] += kd.w * ve.w;
        }
        if (t < 64) {
            float s = 0.f;
            #pragma unroll 8
            for (int l = 0; l < 64; l++) s += kf[buf][l][t];
            ks_acc += s;
        }
        // next phase writes the OTHER buffer; this buffer is rewritten only at
        // ph+2, after the ph+1 barrier confirmed all reads here finished.
    }
    float* dst = kvpart + ((size_t)(sc & 3) * 16 + h) * 4096;
    #pragma unroll
    for (int i = 0; i < 4; i++)
        #pragma unroll
        for (int j = 0; j < 4; j++)
            atomicAdd(&dst[(d0 + i) * 64 + e0 + j], acc[i * 4 + j]);
    if (t < 64) atomicAdd(&ksum[h * 64 + t], ks_acc);
}

// K3: pooled_q fused (threads t<64 run pool_q's EXACT serial loop -> bit-identical),
// then scores (f64 accum, same order) + top-25 rank select, ballot compaction.
__global__ __launch_bounds__(256) void score_topk(const float* __restrict__ q,
                                                  const float* __restrict__ pk,
                                                  int* __restrict__ lut) {
    __shared__ __align__(16) float pq_s[64];
    __shared__ __align__(16) float s_s[256];
    __shared__ int wcnt[4];
    int b = blockIdx.x;            // h*128 + m
    int h = b >> 7, m = b & 127;
    int t = threadIdx.x;
    int lane = t & 63, w = t >> 6;
    if (t < 64) {
        const float* base = q + (size_t)m * 64 * HD + h * 64 + t;
        float s = 0.f;
        #pragma unroll 8
        for (int r = 0; r < 64; r++) s += base[(size_t)r * HD];
        pq_s[t] = s * (1.f / 64.f);
    }
    __syncthreads();
    const float* kr = pk + ((size_t)h * 256 + t) * 64;
    double acc = 0.0;
    #pragma unroll 8
    for (int d = 0; d < 64; d++) acc += (double)pq_s[d] * (double)kr[d];
    float sc = (float)acc;
    s_s[t] = sc;
    __syncthreads();
    int cnt = 0;
    float si = sc;
    #pragma unroll 4
    for (int j4 = 0; j4 < 64; j4++) {
        float4 sv = *(const float4*)&s_s[j4 * 4];
        int j = j4 * 4;
        cnt += (sv.x > si) || (sv.x == si && (j + 0) < t);
        cnt += (sv.y > si) || (sv.y == si && (j + 1) < t);
        cnt += (sv.z > si) || (sv.z == si && (j + 2) < t);
        cnt += (sv.w > si) || (sv.w == si && (j + 3) < t);
    }
    bool sel = cnt < TSEL;
    unsigned long long bal = __ballot(sel);
    if (lane == 0) wcnt[w] = __popcll(bal);
    __syncthreads();
    if (sel) {
        int off = __popcll(bal & ((1ull << lane) - 1ull));
        for (int i = 0; i < w; i++) off += wcnt[i];
        lut[(size_t)b * TSEL + off] = t;
    }
}

// K5: reduce partials + KWt = kvsum · W^T (bf16, transposed layout).
__global__ __launch_bounds__(256) void kw_mul(const float* __restrict__ kvpart,
                                              const float* __restrict__ W,
                                              short* __restrict__ kwt) {
    __shared__ __align__(16) float kv[16][68];
    __shared__ __align__(16) float wsm[64][68];
    int h = blockIdx.x >> 2, dq = blockIdx.x & 3;
    int t = threadIdx.x;
    for (int i = t; i < 1024; i += 256) {
        int dl = i >> 6, e = i & 63;
        float s = 0.f;
        #pragma unroll
        for (int p = 0; p < 4; p++)
            s += kvpart[((size_t)p * 16 + h) * 4096 + (dq * 16 + dl) * 64 + e];
        kv[dl][e] = s;
    }
    for (int i = t; i < 4096; i += 256) wsm[i >> 6][i & 63] = W[i];
    __syncthreads();
    int lane = t & 63, wi = t >> 6;
    int dl = lane & 15;
    int db = wi * 16 + (lane >> 4) * 4;
    #pragma unroll
    for (int j = 0; j < 4; j++) {
        int dd = db + j;
        float a = 0.f;
        #pragma unroll
        for (int e4 = 0; e4 < 16; e4++) {
            float4 kq = *(const float4*)&kv[dl][e4 * 4];
            float4 wq = *(const float4*)&wsm[dd][e4 * 4];
            a += kq.x * wq.x + kq.y * wq.y + kq.z * wq.z + kq.w * wq.w;
        }
        kwt[(size_t)h * 4096 + dd * 64 + dq * 16 + dl] = f2bf(a);
    }
}

// K6: fused block-sparse attention + linear branch.
// This round (T3/T4): 3 LDS buffers, prefetch depth 2, counted s_waitcnt
// vmcnt(2) + raw s_barrier at tile boundary (never drain to 0 mid-loop);
// B2 s_barrier REMOVED (Pl rows are wave-private; lgkmcnt(0) suffices);
// Pl stride padded 40 -> 44 (write conflicts 8-way -> 4-way, read near-min).
// All arithmetic unchanged -> bit-identical output.
__global__ __launch_bounds__(256) void sparse_attn_mfma(const float* __restrict__ q,
                                                        const short* __restrict__ kswz,
                                                        const short* __restrict__ vswz,
                                                        const int* __restrict__ lut,
                                                        const short* __restrict__ kwt,
                                                        const float* __restrict__ ksum,
                                                        const float* __restrict__ bproj,
                                                        float* __restrict__ out) {
    __shared__ __align__(16) short Kb[3][2048];
    __shared__ __align__(16) short Vb[3][2048];
    __shared__ __align__(16) short Pl[64][44];
    __shared__ int lut_s[TSEL];

    int b = blockIdx.x;
    int x = b & 7, jj = b >> 3;
    int h = x * 2 + (jj >> 7);       // XCD-affine
    int m = jj & 127;
    int t = threadIdx.x;
    int lane = t & 63, w = t >> 6;
    int l15 = lane & 15, quad = lane >> 4;

    if (t < TSEL) lut_s[t] = lut[(size_t)(h * 128 + m) * TSEL + t];
    __syncthreads();

    {   // stage tile0 -> buf0; KWt -> Kb[1]+Vb[1] (overlay, consumed pre-loop)
        size_t base = (size_t)(h * 256 + lut_s[0]) * 2048;
        load_lds16(kswz + base + t * 8, &Kb[0][t * 8]);
        load_lds16(vswz + base + t * 8, &Vb[0][t * 8]);
        load_lds16(kwt + (size_t)h * 4096 + t * 8, &Kb[1][t * 8]);
        load_lds16(kwt + (size_t)h * 4096 + 2048 + t * 8, &Vb[1][t * 8]);
    }

    const float* qrow = q + (size_t)(m * 64 + w * 16 + l15) * HD + h * 64;
    float4 x0 = *(const float4*)(qrow + quad * 8);
    float4 x1 = *(const float4*)(qrow + quad * 8 + 4);
    float4 x2 = *(const float4*)(qrow + 32 + quad * 8);
    float4 x3 = *(const float4*)(qrow + 32 + quad * 8 + 4);
    bf16x8 qa[2];
    qa[0] = cvt8(x0, x1);
    qa[1] = cvt8(x2, x3);

    float mx = fmaxf(fmaxf(fmaxf(x0.x, x0.y), fmaxf(x0.z, x0.w)),
                     fmaxf(fmaxf(x1.x, x1.y), fmaxf(x1.z, x1.w)));
    mx = fmaxf(mx, fmaxf(fmaxf(fmaxf(x2.x, x2.y), fmaxf(x2.z, x2.w)),
                         fmaxf(fmaxf(x3.x, x3.y), fmaxf(x3.z, x3.w))));
    mx = fmaxf(mx, __shfl_xor(mx, 16, 64));
    mx = fmaxf(mx, __shfl_xor(mx, 32, 64));
    x0.x = __expf(x0.x - mx); x0.y = __expf(x0.y - mx); x0.z = __expf(x0.z - mx); x0.w = __expf(x0.w - mx);
    x1.x = __expf(x1.x - mx); x1.y = __expf(x1.y - mx); x1.z = __expf(x1.z - mx); x1.w = __expf(x1.w - mx);
    x2.x = __expf(x2.x - mx); x2.y = __expf(x2.y - mx); x2.z = __expf(x2.z - mx); x2.w = __expf(x2.w - mx);
    x3.x = __expf(x3.x - mx); x3.y = __expf(x3.y - mx); x3.z = __expf(x3.z - mx); x3.w = __expf(x3.w - mx);
    float sm = (x0.x + x0.y + x0.z + x0.w) + (x1.x + x1.y + x1.z + x1.w)
             + (x2.x + x2.y + x2.z + x2.w) + (x3.x + x3.y + x3.z + x3.w);
    sm += __shfl_xor(sm, 16, 64);
    sm += __shfl_xor(sm, 32, 64);
    float qsc = 1.f / sm;
    float4 ka0 = *(const float4*)(ksum + h * 64 + quad * 8);
    float4 ka1 = *(const float4*)(ksum + h * 64 + quad * 8 + 4);
    float4 ka2 = *(const float4*)(ksum + h * 64 + 32 + quad * 8);
    float4 ka3 = *(const float4*)(ksum + h * 64 + 32 + quad * 8 + 4);
    float dq = x0.x * ka0.x + x0.y * ka0.y + x0.z * ka0.z + x0.w * ka0.w
             + x1.x * ka1.x + x1.y * ka1.y + x1.z * ka1.z + x1.w * ka1.w
             + x2.x * ka2.x + x2.y * ka2.y + x2.z * ka2.z + x2.w * ka2.w
             + x3.x * ka3.x + x3.y * ka3.y + x3.z * ka3.z + x3.w * ka3.w;
    dq += __shfl_xor(dq, 16, 64);
    dq += __shfl_xor(dq, 32, 64);
    float invd = 1.f / (dq * qsc + 1e-6f);
    x0.x *= qsc; x0.y *= qsc; x0.z *= qsc; x0.w *= qsc;
    x1.x *= qsc; x1.y *= qsc; x1.z *= qsc; x1.w *= qsc;
    x2.x *= qsc; x2.y *= qsc; x2.z *= qsc; x2.w *= qsc;
    x3.x *= qsc; x3.y *= qsc; x3.z *= qsc; x3.w *= qsc;
    bf16x8 qf[2];
    qf[0] = cvt8(x0, x1);
    qf[1] = cvt8(x2, x3);

    __syncthreads();                 // full drain: tile0 + KWt visible

    f32x4 Ol[4];
    #pragma unroll
    for (int dt = 0; dt < 4; dt++) Ol[dt] = (f32x4){0.f, 0.f, 0.f, 0.f};
    __builtin_amdgcn_s_setprio(1);
    #pragma unroll
    for (int dt = 0; dt < 4; dt++) {
        #pragma unroll
        for (int kc = 0; kc < 2; kc++) {
            int flat = (dt * 16 + l15) * 64 + kc * 32 + quad * 8;
            bf16x8 a = (dt < 2) ? *(const bf16x8*)&Kb[1][flat]
                                : *(const bf16x8*)&Vb[1][flat - 2048];
            Ol[dt] = __builtin_amdgcn_mfma_f32_16x16x32_bf16(a, qf[kc], Ol[dt], 0, 0, 0);
        }
    }
    __builtin_amdgcn_s_setprio(0);

    __syncthreads();                 // all waves done reading KWt region
    {   // stage tile1 -> buf1 (overwrites KWt overlay)
        size_t base = (size_t)(h * 256 + lut_s[1]) * 2048;
        load_lds16(kswz + base + t * 8, &Kb[1][t * 8]);
        load_lds16(vswz + base + t * 8, &Vb[1][t * 8]);
    }

    f32x4 O[4];
    #pragma unroll
    for (int dt = 0; dt < 4; dt++) O[dt] = (f32x4){0.f, 0.f, 0.f, 0.f};
    float l_i = 0.f;
    const f32x4 z = (f32x4){0.f, 0.f, 0.f, 0.f};
    const float EC = 1.44269504f * 0.125f;   // exact: 0.125*log2e, single rounding

    int bc = 0;                      // current buffer = ti % 3
    for (int ti = 0; ti < TSEL; ti++) {
        if (ti > 0) {
            // counted wait: drain only tile-ti's 2 loads; keep ti+1's in flight.
            if (ti < TSEL - 1) asm volatile("s_waitcnt vmcnt(2)" ::: "memory");
            else               asm volatile("s_waitcnt vmcnt(0)" ::: "memory");
            __builtin_amdgcn_s_barrier();
            __builtin_amdgcn_sched_barrier(0);
        }
        if (ti + 2 < TSEL) {         // prefetch depth 2 into buf (ti+2)%3
            int bs = bc ? bc - 1 : 2;
            size_t base = (size_t)(h * 256 + lut_s[ti + 2]) * 2048;
            load_lds16(kswz + base + t * 8, &Kb[bs][t * 8]);
            load_lds16(vswz + base + t * 8, &Vb[bs][t * 8]);
        }
        // S^T = K · Q^T
        int r0 = l15, r1 = 16 + l15;
        bf16x8 a00 = *(const bf16x8*)&Kb[bc][(r0 * 8 + (quad ^ (r0 & 7))) * 8];
        bf16x8 a01 = *(const bf16x8*)&Kb[bc][(r0 * 8 + ((4 + quad) ^ (r0 & 7))) * 8];
        bf16x8 a10 = *(const bf16x8*)&Kb[bc][(r1 * 8 + (quad ^ (r1 & 7))) * 8];
        bf16x8 a11 = *(const bf16x8*)&Kb[bc][(r1 * 8 + ((4 + quad) ^ (r1 & 7))) * 8];
        __builtin_amdgcn_s_setprio(1);
        f32x4 s0 = __builtin_amdgcn_mfma_f32_16x16x32_bf16(a00, qa[0], z, 0, 0, 0);
        s0 = __builtin_amdgcn_mfma_f32_16x16x32_bf16(a01, qa[1], s0, 0, 0, 0);
        f32x4 s1 = __builtin_amdgcn_mfma_f32_16x16x32_bf16(a10, qa[0], z, 0, 0, 0);
        s1 = __builtin_amdgcn_mfma_f32_16x16x32_bf16(a11, qa[1], s1, 0, 0, 0);
        __builtin_amdgcn_s_setprio(0);

        float p0[4], p1[4];
        float lsum = 0.f;
        #pragma unroll
        for (int r = 0; r < 4; r++) {
            p0[r] = exp2a(s0[r] * EC);
            p1[r] = exp2a(s1[r] * EC);
            lsum += p0[r] + p1[r];
        }
        lsum += __shfl_xor(lsum, 16, 64);
        lsum += __shfl_xor(lsum, 32, 64);
        l_i += lsum;

        uint2 pkA, pkB;
        pkA.x = cvtpk(p0[0], p0[1]); pkA.y = cvtpk(p0[2], p0[3]);
        pkB.x = cvtpk(p1[0], p1[1]); pkB.y = cvtpk(p1[2], p1[3]);
        *(uint2*)&Pl[w * 16 + l15][quad * 4] = pkA;
        *(uint2*)&Pl[w * 16 + l15][16 + quad * 4] = pkB;

        // Pl rows are wave-private: no s_barrier needed, only write->read order.
        asm volatile("s_waitcnt lgkmcnt(0)" ::: "memory");
        __builtin_amdgcn_sched_barrier(0);

        bf16x8 pb = *(const bf16x8*)&Pl[w * 16 + l15][quad * 8];
        __builtin_amdgcn_s_setprio(1);
        #pragma unroll
        for (int dt = 0; dt < 4; dt++) {
            int d = dt * 16 + l15;
            bf16x8 va = *(const bf16x8*)&Vb[bc][(d * 4 + (quad ^ ((d >> 1) & 3))) * 8];
            O[dt] = __builtin_amdgcn_mfma_f32_16x16x32_bf16(va, pb, O[dt], 0, 0, 0);
        }
        __builtin_amdgcn_s_setprio(0);

        bc++; if (bc == 3) bc = 0;
    }

    float inv = 1.f / l_i;
    float* dst = out + (size_t)(m * 64 + w * 16 + l15) * HD + h * 64;
    #pragma unroll
    for (int dt = 0; dt < 4; dt++) {
        float4 bv = *(const float4*)(bproj + dt * 16 + quad * 4);
        float4 o;
        o.x = O[dt][0] * inv + Ol[dt][0] * invd + bv.x;
        o.y = O[dt][1] * inv + Ol[dt][1] * invd + bv.y;
        o.z = O[dt][2] * inv + Ol[dt][2] * invd + bv.z;
        o.w = O[dt][3] * inv + Ol[dt][3] * invd + bv.w;
        *(float4*)(dst + dt * 16 + quad * 4) = o;
    }
}

extern "C" void kernel_launch(void* const* d_in, const int* in_sizes, int n_in,
                              void* d_out, int out_size, void* d_ws, size_t ws_size,
                              hipStream_t stream) {
    const float* q  = (const float*)d_in[0];
    const float* k  = (const float*)d_in[1];
    const float* v  = (const float*)d_in[2];
    const float* W  = (const float*)d_in[3];
    const float* bp = (const float*)d_in[4];
    float* out = (float*)d_out;
    float* ws = (float*)d_ws;

    float* kvpart = ws + OFF_KVPART;
    float* ksum   = ws + OFF_KSUM;
    float* pk     = ws + OFF_PK;
    short* kwt    = (short*)(ws + OFF_KWT);
    short* kswz   = (short*)(ws + OFF_KSWZ);
    short* vswz   = kswz + (size_t)16 * 256 * 2048;
    int*   lut    = (int*)(ws + OFF_LUT);  // overlays kvpart; written after kw_mul consumed it

    hipMemsetAsync(ws, 0, OFF_ZEND * sizeof(float), stream);
    prep_lin<<<512, 256, 0, stream>>>(k, v, kswz, vswz, pk, kvpart, ksum);
    kw_mul<<<64, 256, 0, stream>>>(kvpart, W, kwt);
    score_topk<<<2048, 256, 0, stream>>>(q, pk, lut);
    sparse_attn_mfma<<<2048, 256, 0, stream>>>(q, kswz, vswz, lut, kwt, ksum, bp, out);
}